// Round 6
// baseline (11215.682 us; speedup 1.0000x reference)
//
#include <hip/hip_runtime.h>
#include <cstddef>
#include <cstdint>

static constexpr int B  = 256;
static constexpr int T  = 64;
static constexpr int D  = 512;
static constexpr int HE = 1024;
static constexpr int L  = 512;

typedef unsigned short ushort_t;
typedef __attribute__((ext_vector_type(8))) short short8;
typedef __attribute__((ext_vector_type(8))) _Float16 f16x8;
typedef __attribute__((ext_vector_type(4))) float f32x4;
typedef __attribute__((ext_vector_type(4))) unsigned short ushort4_t;

// lo planes stored pre-scaled by 2^11 (keeps fp16 lo normal; MFMA may flush
// subnormals). Epilogue: v = acc_hi + 2^-11 * acc_lo.
static constexpr float LO_SCALE   = 2048.0f;
static constexpr float LO_UNSCALE = 4.8828125e-4f;   // 1/2048

__device__ __forceinline__ float sigmoidf_(float x) { return 1.0f / (1.0f + expf(-x)); }

struct hfp { ushort_t hi, lo; };
__device__ __forceinline__ hfp f16_split(float v) {
    _Float16 h = (_Float16)v;
    _Float16 l = (_Float16)((v - (float)h) * LO_SCALE);
    hfp r;
    r.hi = __builtin_bit_cast(ushort_t, h);
    r.lo = __builtin_bit_cast(ushort_t, l);
    return r;
}

// ======================= weight/bias packing =======================
// gate-packed col p -> src row ((p>>4)&3)*H + (p>>6)*16 + (p&15); H==0 -> identity
__global__ void pack_w(const float* __restrict__ src, ushort_t* __restrict__ hi,
                       ushort_t* __restrict__ lo, int Np, int K, int H)
{
    int idx = blockIdx.x * 256 + threadIdx.x;
    int pc = K >> 2;
    if (idx >= Np * pc) return;
    int p = idx / pc, kc = (idx - p * pc) << 2;
    int srow = p;
    if (H) srow = ((p >> 4) & 3) * H + (p >> 6) * 16 + (p & 15);
    float4 v = *(const float4*)(src + (size_t)srow * K + kc);
    ushort4_t h, l;
    hfp a;
    a = f16_split(v.x); h[0] = a.hi; l[0] = a.lo;
    a = f16_split(v.y); h[1] = a.hi; l[1] = a.lo;
    a = f16_split(v.z); h[2] = a.hi; l[2] = a.lo;
    a = f16_split(v.w); h[3] = a.hi; l[3] = a.lo;
    *(ushort4_t*)(hi + (size_t)p * K + kc) = h;
    *(ushort4_t*)(lo + (size_t)p * K + kc) = l;
}

__global__ void pack_bias(const float* __restrict__ b1, const float* __restrict__ b2,
                          float* __restrict__ dst, int H)
{
    int p = blockIdx.x * 256 + threadIdx.x;
    if (p >= 4 * H) return;
    int srow = ((p >> 4) & 3) * H + (p >> 6) * 16 + (p & 15);
    dst[p] = b1[srow] + b2[srow];
}

// x [B][T][D] fp32 -> t-major f16 pair planes [T*B][D]
__global__ void conv_x(const float* __restrict__ x, ushort_t* __restrict__ xh,
                       ushort_t* __restrict__ xl)
{
    int idx = blockIdx.x * 256 + threadIdx.x;
    if (idx >= T * B * D / 4) return;
    int r = idx >> 7;               // D/4 = 128
    int kc = (idx & 127) << 2;
    int t = r >> 8, b = r & 255;
    float4 v = *(const float4*)(x + ((size_t)b * T + t) * D + kc);
    ushort4_t h, l;
    hfp a;
    a = f16_split(v.x); h[0] = a.hi; l[0] = a.lo;
    a = f16_split(v.y); h[1] = a.hi; l[1] = a.lo;
    a = f16_split(v.z); h[2] = a.hi; l[2] = a.lo;
    a = f16_split(v.w); h[3] = a.hi; l[3] = a.lo;
    *(ushort4_t*)(xh + (size_t)r * D + kc) = h;
    *(ushort4_t*)(xl + (size_t)r * D + kc) = l;
}

// ======================= fp16x3 MFMA GEMM =======================
struct PairOp { const ushort_t *Ahi, *Alo; int lda; const ushort_t *Whi, *Wlo; int ldw; int K; };
struct MArgs {
    PairOp op[3];
    const float* ci0; int ld0;      // acc init (packed cols); ld 0 = broadcast row
    const float* ci1; int ld1;
    int mode;                        // 0 plain, 1 lstm, 2 plain + prob-permute rows
    // lstm
    const float* cin; int cinLd;
    float* cout; int coutLd;
    ushort_t *hHi, *hLo; int hLd;
    // plain
    float* out; int outLd;
    ushort_t *pHi, *pLo; int pLd;   // optional pair copy of plain output
};

__device__ __forceinline__ f32x4 MFH(short8 a, short8 w, f32x4 c) {
    return __builtin_amdgcn_mfma_f32_16x16x32_f16(
        __builtin_bit_cast(f16x8, a), __builtin_bit_cast(f16x8, w), c, 0, 0, 0);
}

// Tile: (WM*MF*16) rows x (WN*64) packed cols. K per op: multiple of 64 (DEEP=0)
// or 128 (DEEP=1). DEEP=1: 4-k-step register pipeline (latency/concurrency).
template<int MF, int WM, int WN, int DEEP>
__global__ __launch_bounds__(WM * WN * 64) void gemm_hx(MArgs ga0, MArgs ga1)
{
    const MArgs& ga = blockIdx.z ? ga1 : ga0;
    const int lane = threadIdx.x & 63;
    const int wid  = threadIdx.x >> 6;
    const int wy = wid / WN, wx = wid % WN;
    const int m_w = blockIdx.y * (WM * MF * 16) + wy * MF * 16;
    const int n_w = blockIdx.x * (WN * 64) + wx * 64;
    const int l15 = lane & 15;
    const int lk8 = (lane >> 4) * 8;
    const int rB  = (lane >> 4) * 4;

    f32x4 accH[MF][4];     // ah*wh
    f32x4 accL[MF][4];     // 2^11*(ah*wl + al*wh)
#pragma unroll
    for (int mf = 0; mf < MF; ++mf)
#pragma unroll
        for (int j = 0; j < 4; ++j) {
            const int p = n_w + j * 16 + l15;
#pragma unroll
            for (int r = 0; r < 4; ++r) {
                const int m = m_w + mf * 16 + rB + r;
                float v = 0.0f;
                if (ga.ci0) v += ga.ci0[(size_t)m * ga.ld0 + p];
                if (ga.ci1) v += ga.ci1[(size_t)m * ga.ld1 + p];
                accH[mf][j][r] = v;
                accL[mf][j][r] = 0.0f;
            }
        }

#pragma unroll 1
    for (int opi = 0; opi < 3; ++opi) {
        const PairOp o = ga.op[opi];
        if (o.Ahi == nullptr || o.K <= 0) continue;
        const ushort_t *aH[MF], *aL[MF], *wH[4], *wL[4];
#pragma unroll
        for (int mf = 0; mf < MF; ++mf) {
            size_t ro = (size_t)(m_w + mf * 16 + l15) * o.lda + lk8;
            aH[mf] = o.Ahi + ro; aL[mf] = o.Alo + ro;
        }
#pragma unroll
        for (int j = 0; j < 4; ++j) {
            size_t ro = (size_t)(n_w + j * 16 + l15) * o.ldw + lk8;
            wH[j] = o.Whi + ro; wL[j] = o.Wlo + ro;
        }
        const int NK = o.K >> 5;

        auto LD = [&](short8* ah, short8* al, short8* wh, short8* wl, int ks) {
#pragma unroll
            for (int mf = 0; mf < MF; ++mf) {
                ah[mf] = *(const short8*)(aH[mf] + ks * 32);
                al[mf] = *(const short8*)(aL[mf] + ks * 32);
            }
#pragma unroll
            for (int j = 0; j < 4; ++j) {
                wh[j] = *(const short8*)(wH[j] + ks * 32);
                wl[j] = *(const short8*)(wL[j] + ks * 32);
            }
        };
        auto MM = [&](short8* ah, short8* al, short8* wh, short8* wl) {
#pragma unroll
            for (int mf = 0; mf < MF; ++mf)
#pragma unroll
                for (int j = 0; j < 4; ++j) {
                    accL[mf][j] = MFH(ah[mf], wl[j], accL[mf][j]);
                    accL[mf][j] = MFH(al[mf], wh[j], accL[mf][j]);
                    accH[mf][j] = MFH(ah[mf], wh[j], accH[mf][j]);
                }
        };

        if constexpr (DEEP) {
            // 4-buffer rotation; requires NK % 4 == 0 and NK >= 8.
            short8 A0[MF], L0[MF], W0[4], V0[4];
            short8 A1[MF], L1[MF], W1[4], V1[4];
            short8 A2[MF], L2[MF], W2[4], V2[4];
            short8 A3[MF], L3[MF], W3[4], V3[4];
            LD(A0, L0, W0, V0, 0);
            LD(A1, L1, W1, V1, 1);
            LD(A2, L2, W2, V2, 2);
            LD(A3, L3, W3, V3, 3);
            int ks = 0;
            for (; ks + 8 <= NK; ks += 4) {
                MM(A0, L0, W0, V0); LD(A0, L0, W0, V0, ks + 4);
                MM(A1, L1, W1, V1); LD(A1, L1, W1, V1, ks + 5);
                MM(A2, L2, W2, V2); LD(A2, L2, W2, V2, ks + 6);
                MM(A3, L3, W3, V3); LD(A3, L3, W3, V3, ks + 7);
            }
            MM(A0, L0, W0, V0);
            MM(A1, L1, W1, V1);
            MM(A2, L2, W2, V2);
            MM(A3, L3, W3, V3);
        } else {
            short8 A0[MF], L0[MF], W0[4], V0[4];
            short8 A1[MF], L1[MF], W1[4], V1[4];
            LD(A0, L0, W0, V0, 0);
            int ks = 0;
            for (; ks + 2 < NK; ks += 2) {
                LD(A1, L1, W1, V1, ks + 1);
                MM(A0, L0, W0, V0);
                LD(A0, L0, W0, V0, ks + 2);
                MM(A1, L1, W1, V1);
            }
            LD(A1, L1, W1, V1, ks + 1);
            MM(A0, L0, W0, V0);
            MM(A1, L1, W1, V1);
        }
    }

    if (ga.mode == 1) {
        const int n = (n_w >> 6) * 16 + l15;      // neuron index
#pragma unroll
        for (int mf = 0; mf < MF; ++mf)
#pragma unroll
            for (int r = 0; r < 4; ++r) {
                const int m = m_w + mf * 16 + rB + r;
                const float gi = accH[mf][0][r] + LO_UNSCALE * accL[mf][0][r];
                const float gf = accH[mf][1][r] + LO_UNSCALE * accL[mf][1][r];
                const float gg = accH[mf][2][r] + LO_UNSCALE * accL[mf][2][r];
                const float go = accH[mf][3][r] + LO_UNSCALE * accL[mf][3][r];
                const float cold = ga.cin[(size_t)m * ga.cinLd + n];
                const float cn = sigmoidf_(gf) * cold + sigmoidf_(gi) * tanhf(gg);
                const float h  = sigmoidf_(go) * tanhf(cn);
                ga.cout[(size_t)m * ga.coutLd + n] = cn;
                hfp hp = f16_split(h);
                ga.hHi[(size_t)m * ga.hLd + n] = hp.hi;
                ga.hLo[(size_t)m * ga.hLd + n] = hp.lo;
            }
    } else {
#pragma unroll
        for (int mf = 0; mf < MF; ++mf)
#pragma unroll
            for (int j = 0; j < 4; ++j) {
                const int p = n_w + j * 16 + l15;
#pragma unroll
                for (int r = 0; r < 4; ++r) {
                    const int m = m_w + mf * 16 + rB + r;
                    const float v = accH[mf][j][r] + LO_UNSCALE * accL[mf][j][r];
                    int dst = m;
                    if (ga.mode == 2) dst = ((m & (B - 1)) << 6) + (m >> 8);  // b*T + t
                    if (ga.out) ga.out[(size_t)dst * ga.outLd + p] = v;
                    if (ga.pHi) {
                        hfp vp = f16_split(v);
                        ga.pHi[(size_t)m * ga.pLd + p] = vp.hi;
                        ga.pLo[(size_t)m * ga.pLd + p] = vp.lo;
                    }
                }
            }
    }
}

// layernorm(mu), softplus(std), z = mu+eps*std -> c0,c1 (fp32) and z f16 pairs
__global__ void latent2(float* __restrict__ mu, float* __restrict__ sd,
                        const float* __restrict__ eps, float* __restrict__ c0,
                        float* __restrict__ c1, ushort_t* __restrict__ zh,
                        ushort_t* __restrict__ zl)
{
    const int b = blockIdx.x, l = threadIdx.x;
    float* mrow = mu + (size_t)b * L;
    float4 v0 = *(const float4*)(mrow + l * 4);
    float4 v1 = *(const float4*)(mrow + 256 + l * 4);
    float s = v0.x + v0.y + v0.z + v0.w + v1.x + v1.y + v1.z + v1.w;
    float q = v0.x * v0.x + v0.y * v0.y + v0.z * v0.z + v0.w * v0.w
            + v1.x * v1.x + v1.y * v1.y + v1.z * v1.z + v1.w * v1.w;
#pragma unroll
    for (int off = 32; off; off >>= 1) { s += __shfl_xor(s, off); q += __shfl_xor(q, off); }
    const float mean = s * (1.0f / 512.0f);
    const float var  = q * (1.0f / 512.0f) - mean * mean;
    const float inv  = rsqrtf(var + 1e-5f);
    v0.x = (v0.x - mean) * inv; v0.y = (v0.y - mean) * inv; v0.z = (v0.z - mean) * inv; v0.w = (v0.w - mean) * inv;
    v1.x = (v1.x - mean) * inv; v1.y = (v1.y - mean) * inv; v1.z = (v1.z - mean) * inv; v1.w = (v1.w - mean) * inv;
    *(float4*)(mrow + l * 4) = v0;
    *(float4*)(mrow + 256 + l * 4) = v1;

    float* srow = sd + (size_t)b * L;
    float4 s0 = *(const float4*)(srow + l * 4);
    float4 s1 = *(const float4*)(srow + 256 + l * 4);
    s0.x = fmaxf(s0.x, 0.0f) + log1pf(expf(-fabsf(s0.x)));
    s0.y = fmaxf(s0.y, 0.0f) + log1pf(expf(-fabsf(s0.y)));
    s0.z = fmaxf(s0.z, 0.0f) + log1pf(expf(-fabsf(s0.z)));
    s0.w = fmaxf(s0.w, 0.0f) + log1pf(expf(-fabsf(s0.w)));
    s1.x = fmaxf(s1.x, 0.0f) + log1pf(expf(-fabsf(s1.x)));
    s1.y = fmaxf(s1.y, 0.0f) + log1pf(expf(-fabsf(s1.y)));
    s1.z = fmaxf(s1.z, 0.0f) + log1pf(expf(-fabsf(s1.z)));
    s1.w = fmaxf(s1.w, 0.0f) + log1pf(expf(-fabsf(s1.w)));
    *(float4*)(srow + l * 4) = s0;
    *(float4*)(srow + 256 + l * 4) = s1;

    const float* erow = eps + (size_t)b * L;
    float4 e0 = *(const float4*)(erow + l * 4);
    float4 e1 = *(const float4*)(erow + 256 + l * 4);
    float4 z0, z1;
    z0.x = v0.x + e0.x * s0.x; z0.y = v0.y + e0.y * s0.y; z0.z = v0.z + e0.z * s0.z; z0.w = v0.w + e0.w * s0.w;
    z1.x = v1.x + e1.x * s1.x; z1.y = v1.y + e1.y * s1.y; z1.z = v1.z + e1.z * s1.z; z1.w = v1.w + e1.w * s1.w;
    *(float4*)(c0 + (size_t)b * L + l * 4) = z0;
    *(float4*)(c0 + (size_t)b * L + 256 + l * 4) = z1;
    *(float4*)(c1 + (size_t)b * L + l * 4) = z0;
    *(float4*)(c1 + (size_t)b * L + 256 + l * 4) = z1;
    ushort4_t h, lo;
    hfp a;
    a = f16_split(z0.x); h[0] = a.hi; lo[0] = a.lo;
    a = f16_split(z0.y); h[1] = a.hi; lo[1] = a.lo;
    a = f16_split(z0.z); h[2] = a.hi; lo[2] = a.lo;
    a = f16_split(z0.w); h[3] = a.hi; lo[3] = a.lo;
    *(ushort4_t*)(zh + (size_t)b * L + l * 4) = h;
    *(ushort4_t*)(zl + (size_t)b * L + l * 4) = lo;
    a = f16_split(z1.x); h[0] = a.hi; lo[0] = a.lo;
    a = f16_split(z1.y); h[1] = a.hi; lo[1] = a.lo;
    a = f16_split(z1.z); h[2] = a.hi; lo[2] = a.lo;
    a = f16_split(z1.w); h[3] = a.hi; lo[3] = a.lo;
    *(ushort4_t*)(zh + (size_t)b * L + 256 + l * 4) = h;
    *(ushort4_t*)(zl + (size_t)b * L + 256 + l * 4) = lo;
}

// in-place softmax + argmax over all B*T rows; one wave per row.
__global__ void softmax_all(float* __restrict__ prob, float* __restrict__ label)
{
    const int r = blockIdx.x, l = threadIdx.x;
    float* row = prob + (size_t)r * D;
    float4 x0 = *(const float4*)(row + l * 4);
    float4 x1 = *(const float4*)(row + 256 + l * 4);
    float m = x0.x; int mi = l * 4;
    { float v; int i;
      v = x0.y; i = l * 4 + 1;       if (v > m) { m = v; mi = i; }
      v = x0.z; i = l * 4 + 2;       if (v > m) { m = v; mi = i; }
      v = x0.w; i = l * 4 + 3;       if (v > m) { m = v; mi = i; }
      v = x1.x; i = 256 + l * 4;     if (v > m) { m = v; mi = i; }
      v = x1.y; i = 256 + l * 4 + 1; if (v > m) { m = v; mi = i; }
      v = x1.z; i = 256 + l * 4 + 2; if (v > m) { m = v; mi = i; }
      v = x1.w; i = 256 + l * 4 + 3; if (v > m) { m = v; mi = i; } }
#pragma unroll
    for (int off = 32; off; off >>= 1) {
        float om = __shfl_xor(m, off);
        int   oi = __shfl_xor(mi, off);
        if (om > m || (om == m && oi < mi)) { m = om; mi = oi; }
    }
    float4 e0, e1;
    e0.x = expf(x0.x - m); e0.y = expf(x0.y - m); e0.z = expf(x0.z - m); e0.w = expf(x0.w - m);
    e1.x = expf(x1.x - m); e1.y = expf(x1.y - m); e1.z = expf(x1.z - m); e1.w = expf(x1.w - m);
    float s = e0.x + e0.y + e0.z + e0.w + e1.x + e1.y + e1.z + e1.w;
#pragma unroll
    for (int off = 32; off; off >>= 1) s += __shfl_xor(s, off);
    const float inv = 1.0f / s;
    e0.x *= inv; e0.y *= inv; e0.z *= inv; e0.w *= inv;
    e1.x *= inv; e1.y *= inv; e1.z *= inv; e1.w *= inv;
    *(float4*)(row + l * 4) = e0;
    *(float4*)(row + 256 + l * 4) = e1;
    if (l == 0) label[r] = (float)mi;
}

// ======================= fp32 fallback path (R2, proven) =======================
struct Op { const float* A; int lda; const float* W; int ldw; int K; };
struct GArgs {
    Op op[3];
    const float* b1; const float* b2;
    float* out; int outLd;
    const float* cin; int cinLd;
    float* cout;
    int H; int gx; int mode; int tOff;
};

__global__ __launch_bounds__(256, 2) void gemm_u(GArgs ga0, GArgs ga1)
{
    const GArgs& ga = blockIdx.z ? ga1 : ga0;
    if ((int)blockIdx.x >= ga.gx) return;
    __shared__ __align__(16) float As[16][68];
    __shared__ __align__(16) float Ws[16][68];
    const int tid = threadIdx.x;
    const int m0 = blockIdx.y * 64;
    const int ty = tid >> 4, tx = tid & 15;
    const int lm = tid >> 2;
    const int lk = (tid & 3) << 2;
    int wrow;
    if (ga.mode == 1) wrow = (lm & 3) * ga.H + blockIdx.x * 16 + (lm >> 2);
    else              wrow = blockIdx.x * 64 + lm;
    float acc[4][4] = {};
    for (int opi = 0; opi < 3; ++opi) {
        const Op o = ga.op[opi];
        if (o.A == nullptr || o.K <= 0) continue;
        const float* Ab = o.A + (size_t)(m0 + lm) * o.lda + lk;
        const float* Wb = o.W + (size_t)wrow * o.ldw + lk;
        for (int kb = 0; kb < o.K; kb += 16) {
            float4 av = *(const float4*)(Ab + kb);
            float4 wv = *(const float4*)(Wb + kb);
            As[lk + 0][lm] = av.x; As[lk + 1][lm] = av.y;
            As[lk + 2][lm] = av.z; As[lk + 3][lm] = av.w;
            Ws[lk + 0][lm] = wv.x; Ws[lk + 1][lm] = wv.y;
            Ws[lk + 2][lm] = wv.z; Ws[lk + 3][lm] = wv.w;
            __syncthreads();
#pragma unroll
            for (int kk = 0; kk < 16; ++kk) {
                float4 a = *(const float4*)&As[kk][ty << 2];
                float4 w = *(const float4*)&Ws[kk][tx << 2];
                acc[0][0] += a.x * w.x; acc[0][1] += a.x * w.y; acc[0][2] += a.x * w.z; acc[0][3] += a.x * w.w;
                acc[1][0] += a.y * w.x; acc[1][1] += a.y * w.y; acc[1][2] += a.y * w.z; acc[1][3] += a.y * w.w;
                acc[2][0] += a.z * w.x; acc[2][1] += a.z * w.y; acc[2][2] += a.z * w.z; acc[2][3] += a.z * w.w;
                acc[3][0] += a.w * w.x; acc[3][1] += a.w * w.y; acc[3][2] += a.w * w.z; acc[3][3] += a.w * w.w;
            }
            __syncthreads();
        }
    }
    if (ga.mode == 1) {
        const int H = ga.H;
        const int n = blockIdx.x * 16 + tx;
        float bb[4];
#pragma unroll
        for (int j = 0; j < 4; ++j) bb[j] = ga.b1[j * H + n] + ga.b2[j * H + n];
#pragma unroll
        for (int i = 0; i < 4; ++i) {
            const int row = m0 + (ty << 2) + i;
            const float gi = acc[i][0] + bb[0];
            const float gf = acc[i][1] + bb[1];
            const float gg = acc[i][2] + bb[2];
            const float go = acc[i][3] + bb[3];
            const float cold = ga.cin[(size_t)row * ga.cinLd + n];
            const float cn = sigmoidf_(gf) * cold + sigmoidf_(gi) * tanhf(gg);
            const float h  = sigmoidf_(go) * tanhf(cn);
            ga.cout[(size_t)row * H + n] = cn;
            ga.out [(size_t)row * ga.outLd + n] = h;
        }
    } else if (ga.mode == 0) {
#pragma unroll
        for (int i = 0; i < 4; ++i) {
            const int row = m0 + (ty << 2) + i;
            float* orow = ga.out + (size_t)row * ga.outLd + blockIdx.x * 64 + (tx << 2);
#pragma unroll
            for (int j = 0; j < 4; ++j) {
                const int col = blockIdx.x * 64 + (tx << 2) + j;
                float v = acc[i][j];
                if (ga.b1) v += ga.b1[col];
                if (ga.b2) v += ga.b2[col];
                orow[j] = v;
            }
        }
    } else {
#pragma unroll
        for (int i = 0; i < 4; ++i) {
            const int row = m0 + (ty << 2) + i;
            const int dst = (row & (B - 1)) * T + (row >> 8) + ga.tOff;
            float* orow = ga.out + (size_t)dst * D + blockIdx.x * 64 + (tx << 2);
#pragma unroll
            for (int j = 0; j < 4; ++j) {
                const int col = blockIdx.x * 64 + (tx << 2) + j;
                orow[j] = acc[i][j] + ga.b1[col];
            }
        }
    }
}

__global__ void latent_finish(float* __restrict__ mu, float* __restrict__ sd,
                              const float* __restrict__ eps, float* __restrict__ z,
                              float* __restrict__ c0, float* __restrict__ c1)
{
    const int b = blockIdx.x, l = threadIdx.x;
    float* mrow = mu + (size_t)b * L;
    float4 v0 = *(const float4*)(mrow + l * 4);
    float4 v1 = *(const float4*)(mrow + 256 + l * 4);
    float s = v0.x + v0.y + v0.z + v0.w + v1.x + v1.y + v1.z + v1.w;
    float q = v0.x * v0.x + v0.y * v0.y + v0.z * v0.z + v0.w * v0.w
            + v1.x * v1.x + v1.y * v1.y + v1.z * v1.z + v1.w * v1.w;
#pragma unroll
    for (int off = 32; off; off >>= 1) { s += __shfl_xor(s, off); q += __shfl_xor(q, off); }
    const float mean = s * (1.0f / 512.0f);
    const float var  = q * (1.0f / 512.0f) - mean * mean;
    const float inv  = rsqrtf(var + 1e-5f);
    v0.x = (v0.x - mean) * inv; v0.y = (v0.y - mean) * inv; v0.z = (v0.z - mean) * inv; v0.w = (v0.w - mean) * inv;
    v1.x = (v1.x - mean) * inv; v1.y = (v1.y - mean) * inv; v1.z = (v1.z - mean) * inv; v1.w = (v1.w - mean) * inv;
    *(float4*)(mrow + l * 4) = v0;
    *(float4*)(mrow + 256 + l * 4) = v1;
    float* srow = sd + (size_t)b * L;
    float4 s0 = *(const float4*)(srow + l * 4);
    float4 s1 = *(const float4*)(srow + 256 + l * 4);
    s0.x = fmaxf(s0.x, 0.0f) + log1pf(expf(-fabsf(s0.x)));
    s0.y = fmaxf(s0.y, 0.0f) + log1pf(expf(-fabsf(s0.y)));
    s0.z = fmaxf(s0.z, 0.0f) + log1pf(expf(-fabsf(s0.z)));
    s0.w = fmaxf(s0.w, 0.0f) + log1pf(expf(-fabsf(s0.w)));
    s1.x = fmaxf(s1.x, 0.0f) + log1pf(expf(-fabsf(s1.x)));
    s1.y = fmaxf(s1.y, 0.0f) + log1pf(expf(-fabsf(s1.y)));
    s1.z = fmaxf(s1.z, 0.0f) + log1pf(expf(-fabsf(s1.z)));
    s1.w = fmaxf(s1.w, 0.0f) + log1pf(expf(-fabsf(s1.w)));
    *(float4*)(srow + l * 4) = s0;
    *(float4*)(srow + 256 + l * 4) = s1;
    const float* erow = eps + (size_t)b * L;
    float4 e0 = *(const float4*)(erow + l * 4);
    float4 e1 = *(const float4*)(erow + 256 + l * 4);
    float4 z0, z1;
    z0.x = v0.x + e0.x * s0.x; z0.y = v0.y + e0.y * s0.y; z0.z = v0.z + e0.z * s0.z; z0.w = v0.w + e0.w * s0.w;
    z1.x = v1.x + e1.x * s1.x; z1.y = v1.y + e1.y * s1.y; z1.z = v1.z + e1.z * s1.z; z1.w = v1.w + e1.w * s1.w;
    *(float4*)(z + (size_t)b * L + l * 4) = z0;
    *(float4*)(z + (size_t)b * L + 256 + l * 4) = z1;
    *(float4*)(c0 + (size_t)b * L + l * 4) = z0;
    *(float4*)(c0 + (size_t)b * L + 256 + l * 4) = z1;
    *(float4*)(c1 + (size_t)b * L + l * 4) = z0;
    *(float4*)(c1 + (size_t)b * L + 256 + l * 4) = z1;
}

// ---------------------------------------------------------------------------
extern "C" void kernel_launch(void* const* d_in, const int* in_sizes, int n_in,
                              void* d_out, int out_size, void* d_ws, size_t ws_size,
                              hipStream_t stream)
{
    const float* x       = (const float*)d_in[0];
    const float* eps     = (const float*)d_in[1];
    const float* We_ih_f = (const float*)d_in[2];
    const float* We_hh_f = (const float*)d_in[3];
    const float* be_ih_f = (const float*)d_in[4];
    const float* be_hh_f = (const float*)d_in[5];
    const float* We_ih_b = (const float*)d_in[6];
    const float* We_hh_b = (const float*)d_in[7];
    const float* be_ih_b = (const float*)d_in[8];
    const float* be_hh_b = (const float*)d_in[9];
    const float* Wmu     = (const float*)d_in[10];
    const float* bmu     = (const float*)d_in[11];
    const float* Wstd    = (const float*)d_in[12];
    const float* bstd    = (const float*)d_in[13];
    const float* Wc_ih0  = (const float*)d_in[14];
    const float* Wc_hh0  = (const float*)d_in[15];
    const float* bc_ih0  = (const float*)d_in[16];
    const float* bc_hh0  = (const float*)d_in[17];
    const float* Wc_ih1  = (const float*)d_in[18];
    const float* Wc_hh1  = (const float*)d_in[19];
    const float* bc_ih1  = (const float*)d_in[20];
    const float* bc_hh1  = (const float*)d_in[21];
    const float* Wcl     = (const float*)d_in[22];
    const float* bcl     = (const float*)d_in[23];
    const float* Wd_ih0  = (const float*)d_in[24];
    const float* Wd_hh0  = (const float*)d_in[25];
    const float* bd_ih0  = (const float*)d_in[26];
    const float* bd_hh0  = (const float*)d_in[27];
    const float* Wd_ih1  = (const float*)d_in[28];
    const float* Wd_hh1  = (const float*)d_in[29];
    const float* bd_ih1  = (const float*)d_in[30];
    const float* bd_hh1  = (const float*)d_in[31];
    const float* Wlog    = (const float*)d_in[32];
    const float* blog    = (const float*)d_in[33];
    (void)in_sizes; (void)n_in; (void)out_size;

    float* out      = (float*)d_out;
    float* prob_out = out;
    float* mu_out   = out + (size_t)B * T * D;
    float* std_out  = mu_out + (size_t)B * L;
    float* lab_out  = std_out + (size_t)B * L;

    // ---------------- new-path workspace layout ----------------
    char* cur = (char*)d_ws;
    auto alignup = [&]() { cur = (char*)(((uintptr_t)cur + 255) & ~(uintptr_t)255); };
    auto aU = [&](size_t elems) { alignup(); ushort_t* p = (ushort_t*)cur; cur += elems * 2; return p; };
    auto aF = [&](size_t elems) { alignup(); float* p = (float*)cur; cur += elems * 4; return p; };

    // weights (hi, lo planes)
    ushort_t* WefIh = aU((size_t)4*HE*D);  ushort_t* WefIl = aU((size_t)4*HE*D);
    ushort_t* WefHh = aU((size_t)4*HE*HE); ushort_t* WefHl = aU((size_t)4*HE*HE);
    ushort_t* WebIh = aU((size_t)4*HE*D);  ushort_t* WebIl = aU((size_t)4*HE*D);
    ushort_t* WebHh = aU((size_t)4*HE*HE); ushort_t* WebHl = aU((size_t)4*HE*HE);
    ushort_t* Wc0Ih = aU((size_t)4*L*L);   ushort_t* Wc0Il = aU((size_t)4*L*L);
    ushort_t* Wc0Hh = aU((size_t)4*L*L);   ushort_t* Wc0Hl = aU((size_t)4*L*L);
    ushort_t* Wc1Ih = aU((size_t)4*L*L);   ushort_t* Wc1Il = aU((size_t)4*L*L);
    ushort_t* Wc1Hh = aU((size_t)4*L*L);   ushort_t* Wc1Hl = aU((size_t)4*L*L);
    ushort_t* Wd0Ih = aU((size_t)4*L*(D+L)); ushort_t* Wd0Il = aU((size_t)4*L*(D+L));
    ushort_t* Wd0Hh = aU((size_t)4*L*L);   ushort_t* Wd0Hl = aU((size_t)4*L*L);
    ushort_t* Wd1Ih = aU((size_t)4*L*L);   ushort_t* Wd1Il = aU((size_t)4*L*L);
    ushort_t* Wd1Hh = aU((size_t)4*L*L);   ushort_t* Wd1Hl = aU((size_t)4*L*L);
    ushort_t* WmuH  = aU((size_t)L*2*HE);  ushort_t* WmuL  = aU((size_t)L*2*HE);
    ushort_t* WstdH = aU((size_t)L*2*HE);  ushort_t* WstdL = aU((size_t)L*2*HE);
    ushort_t* WclH  = aU((size_t)L*L);     ushort_t* WclL  = aU((size_t)L*L);
    ushort_t* WlogH = aU((size_t)D*L);     ushort_t* WlogL = aU((size_t)D*L);
    // activations
    ushort_t* xh = aU((size_t)T*B*D);      ushort_t* xl = aU((size_t)T*B*D);
    ushort_t* hfh[2] = { aU((size_t)B*HE), aU((size_t)B*HE) };
    ushort_t* hfl[2] = { aU((size_t)B*HE), aU((size_t)B*HE) };
    ushort_t* hbh[2] = { aU((size_t)B*HE), aU((size_t)B*HE) };
    ushort_t* hbl[2] = { aU((size_t)B*HE), aU((size_t)B*HE) };
    ushort_t* zh = aU((size_t)B*L);        ushort_t* zl = aU((size_t)B*L);
    ushort_t* h0h[2] = { aU((size_t)B*L), aU((size_t)B*L) };
    ushort_t* h0l[2] = { aU((size_t)B*L), aU((size_t)B*L) };
    ushort_t* ftsH = aU((size_t)B*4*L);    ushort_t* ftsL = aU((size_t)B*4*L);
    ushort_t* featH = aU((size_t)B*4*L);   ushort_t* featL = aU((size_t)B*4*L);
    ushort_t* hd1h[2] = { aU((size_t)B*L), aU((size_t)B*L) };
    ushort_t* hd1l[2] = { aU((size_t)B*L), aU((size_t)B*L) };
    ushort_t* slabH = aU((size_t)T*B*L);   ushort_t* slabL = aU((size_t)T*B*L);
    // fp32 state
    float* cf   = aF((size_t)B*HE);
    float* cb   = aF((size_t)B*HE);
    float* zbuf = aF((size_t)B*HE);
    float* c0   = aF((size_t)B*L);
    float* c1   = aF((size_t)B*L);
    float* cd1  = aF((size_t)B*L);
    float* cd2  = aF((size_t)B*L);
    float* featF = aF((size_t)B*4*L);
    float* bEF = aF((size_t)4*HE);
    float* bEB = aF((size_t)4*HE);
    float* bC0 = aF((size_t)4*L);
    float* bC1 = aF((size_t)4*L);
    float* bD0 = aF((size_t)4*L);
    float* bD1 = aF((size_t)4*L);
    const size_t need = (size_t)(cur - (char*)d_ws);

    if (need <= ws_size) {
        // ==================== fp16x3 MFMA path ====================
        auto PK = [&](const float* s, ushort_t* h, ushort_t* l, int Np, int K, int H) {
            int tot = Np * (K >> 2);
            pack_w<<<(tot + 255) / 256, 256, 0, stream>>>(s, h, l, Np, K, H);
        };
        PK(We_ih_f, WefIh, WefIl, 4*HE, D, HE);
        PK(We_hh_f, WefHh, WefHl, 4*HE, HE, HE);
        PK(We_ih_b, WebIh, WebIl, 4*HE, D, HE);
        PK(We_hh_b, WebHh, WebHl, 4*HE, HE, HE);
        PK(Wc_ih0, Wc0Ih, Wc0Il, 4*L, L, L);
        PK(Wc_hh0, Wc0Hh, Wc0Hl, 4*L, L, L);
        PK(Wc_ih1, Wc1Ih, Wc1Il, 4*L, L, L);
        PK(Wc_hh1, Wc1Hh, Wc1Hl, 4*L, L, L);
        PK(Wd_ih0, Wd0Ih, Wd0Il, 4*L, D+L, L);
        PK(Wd_hh0, Wd0Hh, Wd0Hl, 4*L, L, L);
        PK(Wd_ih1, Wd1Ih, Wd1Il, 4*L, L, L);
        PK(Wd_hh1, Wd1Hh, Wd1Hl, 4*L, L, L);
        PK(Wmu,  WmuH,  WmuL,  L, 2*HE, 0);
        PK(Wstd, WstdH, WstdL, L, 2*HE, 0);
        PK(Wcl,  WclH,  WclL,  L, L, 0);
        PK(Wlog, WlogH, WlogL, D, L, 0);
        pack_bias<<<(4*HE + 255) / 256, 256, 0, stream>>>(be_ih_f, be_hh_f, bEF, HE);
        pack_bias<<<(4*HE + 255) / 256, 256, 0, stream>>>(be_ih_b, be_hh_b, bEB, HE);
        pack_bias<<<(4*L + 255) / 256, 256, 0, stream>>>(bc_ih0, bc_hh0, bC0, L);
        pack_bias<<<(4*L + 255) / 256, 256, 0, stream>>>(bc_ih1, bc_hh1, bC1, L);
        pack_bias<<<(4*L + 255) / 256, 256, 0, stream>>>(bd_ih0, bd_hh0, bD0, L);
        pack_bias<<<(4*L + 255) / 256, 256, 0, stream>>>(bd_ih1, bd_hh1, bD1, L);
        conv_x<<<(T*B*D/4 + 255) / 256, 256, 0, stream>>>(x, xh, xl);
        (void)hipMemsetAsync(zbuf, 0, (size_t)B * HE * sizeof(float), stream);

        // ---------- encoder: 2048 1-wave blocks, deep pipeline ----------
        for (int t = 0; t < T; ++t) {
            MArgs f{};
            f.op[0] = { xh + (size_t)t*B*D, xl + (size_t)t*B*D, D, WefIh, WefIl, D, D };
            if (t) f.op[1] = { hfh[t&1], hfl[t&1], HE, WefHh, WefHl, HE, HE };
            f.ci0 = bEF; f.ld0 = 0;
            f.mode = 1;
            f.cin = t ? cf : zbuf; f.cinLd = HE;
            f.cout = cf; f.coutLd = HE;
            f.hHi = hfh[(t+1)&1]; f.hLo = hfl[(t+1)&1]; f.hLd = HE;
            MArgs b = f;
            b.op[0] = { xh + (size_t)(T-1-t)*B*D, xl + (size_t)(T-1-t)*B*D, D, WebIh, WebIl, D, D };
            if (t) b.op[1] = { hbh[t&1], hbl[t&1], HE, WebHh, WebHl, HE, HE };
            b.ci0 = bEB;
            b.cin = t ? cb : zbuf;
            b.cout = cb;
            b.hHi = hbh[(t+1)&1]; b.hLo = hbl[(t+1)&1];
            gemm_hx<1,1,1,1><<<dim3(4*HE/64, B/16, 2), 64, 0, stream>>>(f, b);
        }

        // ---------- latent ----------
        {
            MArgs m{};
            m.op[0] = { hfh[0], hfl[0], HE, WmuH, WmuL, 2*HE, HE };
            m.op[1] = { hbh[0], hbl[0], HE, WmuH + HE, WmuL + HE, 2*HE, HE };
            m.ci0 = bmu; m.ld0 = 0; m.mode = 0; m.out = mu_out; m.outLd = L;
            MArgs s = m;
            s.op[0].Whi = WstdH; s.op[0].Wlo = WstdL;
            s.op[1].Whi = WstdH + HE; s.op[1].Wlo = WstdL + HE;
            s.ci0 = bstd; s.out = std_out;
            gemm_hx<1,1,1,1><<<dim3(L/64, B/16, 2), 64, 0, stream>>>(m, s);
            latent2<<<B, 64, 0, stream>>>(mu_out, std_out, eps, c0, c1, zh, zl);
        }

        // ---------- conductor ----------
        for (int bar = 0; bar < 4; ++bar) {
            MArgs a{};
            a.op[0] = { zh, zl, L, Wc0Ih, Wc0Il, L, L };
            a.op[1] = { bar ? h0h[(bar-1)&1] : zh, bar ? h0l[(bar-1)&1] : zl, L, Wc0Hh, Wc0Hl, L, L };
            a.ci0 = bC0; a.ld0 = 0; a.mode = 1;
            a.cin = c0; a.cinLd = L; a.cout = c0; a.coutLd = L;
            a.hHi = h0h[bar&1]; a.hLo = h0l[bar&1]; a.hLd = L;
            gemm_hx<1,1,1,1><<<dim3(4*L/64, B/16, 1), 64, 0, stream>>>(a, a);
            MArgs a2{};
            a2.op[0] = { h0h[bar&1], h0l[bar&1], L, Wc1Ih, Wc1Il, L, L };
            if (bar) a2.op[1] = { ftsH + (size_t)(bar-1)*L, ftsL + (size_t)(bar-1)*L, 4*L, Wc1Hh, Wc1Hl, L, L };
            else     a2.op[1] = { zh, zl, L, Wc1Hh, Wc1Hl, L, L };
            a2.ci0 = bC1; a2.ld0 = 0; a2.mode = 1;
            a2.cin = c1; a2.cinLd = L; a2.cout = c1; a2.coutLd = L;
            a2.hHi = ftsH + (size_t)bar*L; a2.hLo = ftsL + (size_t)bar*L; a2.hLd = 4*L;
            gemm_hx<1,1,1,1><<<dim3(4*L/64, B/16, 1), 64, 0, stream>>>(a2, a2);
        }
        {   // feat = feats @ Wcl^T + bcl (fp32 + pairs)
            MArgs af{};
            af.op[0] = { ftsH, ftsL, L, WclH, WclL, L, L };
            af.ci0 = bcl; af.ld0 = 0; af.mode = 0;
            af.out = featF; af.outLd = L;
            af.pHi = featH; af.pLo = featL; af.pLd = L;
            gemm_hx<1,1,1,1><<<dim3(L/64, B*4/16, 1), 64, 0, stream>>>(af, af);
        }

        // ---------- decoder ----------
        for (int t = 0; t < T; ++t) {
            const int bar = t >> 4;
            const bool rs = (t & 15) == 0;
            const float* cinF = featF + (size_t)bar * L;

            MArgs g1{};
            if (t) g1.op[0] = { xh + (size_t)(t-1)*B*D, xl + (size_t)(t-1)*B*D, D, Wd0Ih, Wd0Il, D+L, D };
            g1.op[1] = { featH + (size_t)bar*L, featL + (size_t)bar*L, 4*L, Wd0Ih + D, Wd0Il + D, D+L, L };
            if (rs) g1.op[2] = { featH + (size_t)bar*L, featL + (size_t)bar*L, 4*L, Wd0Hh, Wd0Hl, L, L };
            else    g1.op[2] = { hd1h[(t-1)&1], hd1l[(t-1)&1], L, Wd0Hh, Wd0Hl, L, L };
            g1.ci0 = bD0; g1.ld0 = 0; g1.mode = 1;
            g1.cin = rs ? cinF : cd1; g1.cinLd = rs ? 4*L : L;
            g1.cout = cd1; g1.coutLd = L;
            g1.hHi = hd1h[t&1]; g1.hLo = hd1l[t&1]; g1.hLd = L;
            gemm_hx<1,1,1,1><<<dim3(4*L/64, B/16, 1), 64, 0, stream>>>(g1, g1);

            MArgs g2{};
            g2.op[0] = { hd1h[t&1], hd1l[t&1], L, Wd1Ih, Wd1Il, L, L };
            if (rs) g2.op[1] = { featH + (size_t)bar*L, featL + (size_t)bar*L, 4*L, Wd1Hh, Wd1Hl, L, L };
            else    g2.op[1] = { slabH + (size_t)(t-1)*B*L, slabL + (size_t)(t-1)*B*L, L, Wd1Hh, Wd1Hl, L, L };
            g2.ci0 = bD1; g2.ld0 = 0; g2.mode = 1;
            g2.cin = rs ? cinF : cd2; g2.cinLd = rs ? 4*L : L;
            g2.cout = cd2; g2.coutLd = L;
            g2.hHi = slabH + (size_t)t*B*L; g2.hLo = slabL + (size_t)t*B*L; g2.hLd = L;
            gemm_hx<1,1,1,1><<<dim3(4*L/64, B/16, 1), 64, 0, stream>>>(g2, g2);
        }

        // ---------- logits (batched, high-parallelism shape) + softmax ----------
        {
            MArgs lg{};
            lg.op[0] = { slabH, slabL, L, WlogH, WlogL, L, L };
            lg.ci0 = blog; lg.ld0 = 0; lg.mode = 2;
            lg.out = prob_out; lg.outLd = D;
            gemm_hx<2,2,2,0><<<dim3(D/128, T*B/64, 1), 256, 0, stream>>>(lg, lg);
        }
        softmax_all<<<B * T, 64, 0, stream>>>(prob_out, lab_out);
        return;
    }

    // ==================== fp32 fallback (R2 path) ====================
    {
        float* w = (float*)d_ws;
        size_t off = 0;
        auto alloc = [&](size_t n) { float* p = w + off; off += n; return p; };
        float* hf0 = alloc((size_t)B * HE);
        float* hb0 = alloc((size_t)B * HE);
        float* cfo = alloc((size_t)B * HE);
        float* cbo = alloc((size_t)B * HE);
        float* hf1 = alloc((size_t)B * HE);
        float* hb1 = alloc((size_t)B * HE);
        float* z   = alloc((size_t)B * L);
        float* cc0 = alloc((size_t)B * L);
        float* cc1 = alloc((size_t)B * L);
        float* h0A = alloc((size_t)B * L);
        float* h0B = alloc((size_t)B * L);
        float* ccd1 = alloc((size_t)B * L);
        float* ccd2 = alloc((size_t)B * L);
        float* hd1a = alloc((size_t)B * L);
        float* hd1b = alloc((size_t)B * L);
        float* feats = alloc((size_t)B * 4 * L);
        float* feat  = alloc((size_t)B * 4 * L);
        const size_t base_need = off;
        const bool batched = ws_size >= (base_need + (size_t)T * B * L + 1024) * sizeof(float);
        float* hd2s = alloc(batched ? (size_t)T * B * L : 2 * (size_t)B * L);

        (void)hipMemsetAsync(hf0, 0, (size_t)4 * B * HE * sizeof(float), stream);
        const dim3 blk(256);
        float* hfb[2] = { hf0, hf1 };
        float* hbb[2] = { hb0, hb1 };

        for (int t = 0; t < T; ++t) {
            GArgs f = {};
            f.op[0] = { x + (size_t)t * D, T * D, We_ih_f, D, D };
            f.op[1] = { hfb[t & 1], HE, We_hh_f, HE, HE };
            f.b1 = be_ih_f; f.b2 = be_hh_f;
            f.out = hfb[(t + 1) & 1]; f.outLd = HE;
            f.cin = cfo; f.cinLd = HE; f.cout = cfo;
            f.H = HE; f.gx = HE / 16; f.mode = 1;
            GArgs b = f;
            b.op[0] = { x + (size_t)(T - 1 - t) * D, T * D, We_ih_b, D, D };
            b.op[1] = { hbb[t & 1], HE, We_hh_b, HE, HE };
            b.b1 = be_ih_b; b.b2 = be_hh_b;
            b.out = hbb[(t + 1) & 1];
            b.cin = cbo; b.cout = cbo;
            gemm_u<<<dim3(HE / 16, B / 64, 2), blk, 0, stream>>>(f, b);
        }
        float* hf = hfb[T & 1];
        float* hb = hbb[T & 1];
        {
            GArgs gm = {};
            gm.op[0] = { hf, HE, Wmu, 2 * HE, HE };
            gm.op[1] = { hb, HE, Wmu + HE, 2 * HE, HE };
            gm.b1 = bmu; gm.out = mu_out; gm.outLd = L; gm.gx = L / 64; gm.mode = 0;
            GArgs gs = gm;
            gs.op[0].W = Wstd; gs.op[1].W = Wstd + HE; gs.b1 = bstd; gs.out = std_out;
            gemm_u<<<dim3(L / 64, B / 64, 2), blk, 0, stream>>>(gm, gs);
            latent_finish<<<B, 64, 0, stream>>>(mu_out, std_out, eps, z, cc0, cc1);
        }
        float* h0buf[2] = { h0A, h0B };
        for (int bar = 0; bar < 4; ++bar) {
            GArgs a = {};
            a.op[0] = { z, L, Wc_ih0, L, L };
            a.op[1] = { bar ? h0buf[(bar - 1) & 1] : z, L, Wc_hh0, L, L };
            a.b1 = bc_ih0; a.b2 = bc_hh0;
            a.out = h0buf[bar & 1]; a.outLd = L;
            a.cin = cc0; a.cinLd = L; a.cout = cc0;
            a.H = L; a.gx = L / 16; a.mode = 1;
            gemm_u<<<dim3(L / 16, B / 64, 1), blk, 0, stream>>>(a, a);
            GArgs a2 = {};
            a2.op[0] = { h0buf[bar & 1], L, Wc_ih1, L, L };
            a2.op[1] = { bar ? feats + (size_t)(bar - 1) * L : z, bar ? 4 * L : L, Wc_hh1, L, L };
            a2.b1 = bc_ih1; a2.b2 = bc_hh1;
            a2.out = feats + (size_t)bar * L; a2.outLd = 4 * L;
            a2.cin = cc1; a2.cinLd = L; a2.cout = cc1;
            a2.H = L; a2.gx = L / 16; a2.mode = 1;
            gemm_u<<<dim3(L / 16, B / 64, 1), blk, 0, stream>>>(a2, a2);
        }
        {
            GArgs af = {};
            af.op[0] = { feats, L, Wcl, L, L };
            af.b1 = bcl; af.out = feat; af.outLd = L; af.gx = L / 64; af.mode = 0;
            gemm_u<<<dim3(L / 64, B * 4 / 64, 1), blk, 0, stream>>>(af, af);
        }
        float* hd1buf[2] = { hd1a, hd1b };
        auto slab = [&](int t) { return batched ? hd2s + (size_t)t * B * L : hd2s + (size_t)(t & 1) * B * L; };
        for (int t = 0; t < T; ++t) {
            const int bar = t >> 4;
            const bool rs = (t & 15) == 0;
            const float* fb = feat + (size_t)bar * L;
            GArgs g1 = {};
            if (t > 0) g1.op[0] = { x + (size_t)(t - 1) * D, T * D, Wd_ih0, D + L, D };
            g1.op[1] = { fb, 4 * L, Wd_ih0 + D, D + L, L };
            g1.op[2] = { rs ? fb : hd1buf[(t - 1) & 1], rs ? 4 * L : L, Wd_hh0, L, L };
            g1.b1 = bd_ih0; g1.b2 = bd_hh0;
            g1.out = hd1buf[t & 1]; g1.outLd = L;
            g1.cin = rs ? fb : ccd1; g1.cinLd = rs ? 4 * L : L; g1.cout = ccd1;
            g1.H = L; g1.gx = L / 16; g1.mode = 1;
            if (!batched && t > 0) {
                GArgs lgx = {};
                lgx.op[0] = { slab(t - 1), L, Wlog, L, L };
                lgx.b1 = blog; lgx.out = prob_out; lgx.outLd = D;
                lgx.gx = D / 64; lgx.mode = 2; lgx.tOff = t - 1;
                gemm_u<<<dim3(L / 16, B / 64, 2), blk, 0, stream>>>(g1, lgx);
            } else {
                gemm_u<<<dim3(L / 16, B / 64, 1), blk, 0, stream>>>(g1, g1);
            }
            GArgs g2 = {};
            g2.op[0] = { hd1buf[t & 1], L, Wd_ih1, L, L };
            g2.op[1] = { rs ? fb : slab(t - 1), rs ? 4 * L : L, Wd_hh1, L, L };
            g2.b1 = bd_ih1; g2.b2 = bd_hh1;
            g2.out = slab(t); g2.outLd = L;
            g2.cin = rs ? fb : ccd2; g2.cinLd = rs ? 4 * L : L; g2.cout = ccd2;
            g2.H = L; g2.gx = L / 16; g2.mode = 1;
            gemm_u<<<dim3(L / 16, B / 64, 1), blk, 0, stream>>>(g2, g2);
        }
        if (batched) {
            GArgs lg = {};
            lg.op[0] = { hd2s, L, Wlog, L, L };
            lg.b1 = blog; lg.out = prob_out; lg.outLd = D;
            lg.gx = D / 64; lg.mode = 2; lg.tOff = 0;
            gemm_u<<<dim3(D / 64, (T * B) / 64, 1), blk, 0, stream>>>(lg, lg);
        } else {
            GArgs lg = {};
            lg.op[0] = { slab(T - 1), L, Wlog, L, L };
            lg.b1 = blog; lg.out = prob_out; lg.outLd = D;
            lg.gx = D / 64; lg.mode = 2; lg.tOff = T - 1;
            gemm_u<<<dim3(D / 64, B / 64, 1), blk, 0, stream>>>(lg, lg);
        }
        softmax_all<<<B * T, 64, 0, stream>>>(prob_out, lab_out);
    }
}

// Round 7
// 9300.007 us; speedup vs baseline: 1.2060x; 1.2060x over previous
//
#include <hip/hip_runtime.h>
#include <cstddef>
#include <cstdint>

static constexpr int B  = 256;
static constexpr int T  = 64;
static constexpr int D  = 512;
static constexpr int HE = 1024;
static constexpr int L  = 512;

typedef unsigned short ushort_t;
typedef __attribute__((ext_vector_type(8))) short short8;
typedef __attribute__((ext_vector_type(8))) _Float16 f16x8;
typedef __attribute__((ext_vector_type(4))) float f32x4;
typedef __attribute__((ext_vector_type(4))) unsigned short ushort4_t;

// lo planes stored pre-scaled by 2^11 (keeps fp16 lo normal; MFMA may flush
// subnormals). Epilogue: v = acc_hi + 2^-11 * acc_lo.
static constexpr float LO_SCALE   = 2048.0f;
static constexpr float LO_UNSCALE = 4.8828125e-4f;   // 1/2048

__device__ __forceinline__ float sigmoidf_(float x) { return 1.0f / (1.0f + expf(-x)); }

struct hfp { ushort_t hi, lo; };
__device__ __forceinline__ hfp f16_split(float v) {
    _Float16 h = (_Float16)v;
    _Float16 l = (_Float16)((v - (float)h) * LO_SCALE);
    hfp r;
    r.hi = __builtin_bit_cast(ushort_t, h);
    r.lo = __builtin_bit_cast(ushort_t, l);
    return r;
}

// ======================= weight/bias packing =======================
// gate-packed col p -> src row ((p>>4)&3)*H + (p>>6)*16 + (p&15); H==0 -> identity
__global__ void pack_w(const float* __restrict__ src, ushort_t* __restrict__ hi,
                       ushort_t* __restrict__ lo, int Np, int K, int H)
{
    int idx = blockIdx.x * 256 + threadIdx.x;
    int pc = K >> 2;
    if (idx >= Np * pc) return;
    int p = idx / pc, kc = (idx - p * pc) << 2;
    int srow = p;
    if (H) srow = ((p >> 4) & 3) * H + (p >> 6) * 16 + (p & 15);
    float4 v = *(const float4*)(src + (size_t)srow * K + kc);
    ushort4_t h, l;
    hfp a;
    a = f16_split(v.x); h[0] = a.hi; l[0] = a.lo;
    a = f16_split(v.y); h[1] = a.hi; l[1] = a.lo;
    a = f16_split(v.z); h[2] = a.hi; l[2] = a.lo;
    a = f16_split(v.w); h[3] = a.hi; l[3] = a.lo;
    *(ushort4_t*)(hi + (size_t)p * K + kc) = h;
    *(ushort4_t*)(lo + (size_t)p * K + kc) = l;
}

__global__ void pack_bias(const float* __restrict__ b1, const float* __restrict__ b2,
                          float* __restrict__ dst, int H)
{
    int p = blockIdx.x * 256 + threadIdx.x;
    if (p >= 4 * H) return;
    int srow = ((p >> 4) & 3) * H + (p >> 6) * 16 + (p & 15);
    dst[p] = b1[srow] + b2[srow];
}

// x [B][T][D] fp32 -> t-major f16 pair planes [T*B][D]
__global__ void conv_x(const float* __restrict__ x, ushort_t* __restrict__ xh,
                       ushort_t* __restrict__ xl)
{
    int idx = blockIdx.x * 256 + threadIdx.x;
    if (idx >= T * B * D / 4) return;
    int r = idx >> 7;               // D/4 = 128
    int kc = (idx & 127) << 2;
    int t = r >> 8, b = r & 255;
    float4 v = *(const float4*)(x + ((size_t)b * T + t) * D + kc);
    ushort4_t h, l;
    hfp a;
    a = f16_split(v.x); h[0] = a.hi; l[0] = a.lo;
    a = f16_split(v.y); h[1] = a.hi; l[1] = a.lo;
    a = f16_split(v.z); h[2] = a.hi; l[2] = a.lo;
    a = f16_split(v.w); h[3] = a.hi; l[3] = a.lo;
    *(ushort4_t*)(xh + (size_t)r * D + kc) = h;
    *(ushort4_t*)(xl + (size_t)r * D + kc) = l;
}

// ======================= fp16x3 MFMA GEMM =======================
struct PairOp { const ushort_t *Ahi, *Alo; int lda; const ushort_t *Whi, *Wlo; int ldw; int K; };
struct MArgs {
    PairOp op[3];
    const float* ci0; int ld0;      // acc init (packed cols); ld 0 = broadcast row
    const float* ci1; int ld1;
    int mode;                        // 0 plain, 1 lstm, 2 plain + prob-permute rows
    // lstm
    const float* cin; int cinLd;
    float* cout; int coutLd;
    ushort_t *hHi, *hLo; int hLd;
    // plain
    float* out; int outLd;
    ushort_t *pHi, *pLo; int pLd;   // optional pair copy of plain output
};

__device__ __forceinline__ f32x4 MFH(short8 a, short8 w, f32x4 c) {
    return __builtin_amdgcn_mfma_f32_16x16x32_f16(
        __builtin_bit_cast(f16x8, a), __builtin_bit_cast(f16x8, w), c, 0, 0, 0);
}

// Tile: (WM*MF*16) rows x (WN*64) packed cols. K per op: multiple of 64 (DEEP=0)
// or 128 (DEEP=1). DEEP=1: 4-k-step register pipeline (latency/concurrency).
template<int MF, int WM, int WN, int DEEP>
__global__ __launch_bounds__(WM * WN * 64) void gemm_hx(MArgs ga0, MArgs ga1)
{
    const MArgs& ga = blockIdx.z ? ga1 : ga0;
    const int lane = threadIdx.x & 63;
    const int wid  = threadIdx.x >> 6;
    const int wy = wid / WN, wx = wid % WN;
    const int m_w = blockIdx.y * (WM * MF * 16) + wy * MF * 16;
    const int n_w = blockIdx.x * (WN * 64) + wx * 64;
    const int l15 = lane & 15;
    const int lk8 = (lane >> 4) * 8;
    const int rB  = (lane >> 4) * 4;

    f32x4 accH[MF][4];     // ah*wh
    f32x4 accL[MF][4];     // 2^11*(ah*wl + al*wh)
#pragma unroll
    for (int mf = 0; mf < MF; ++mf)
#pragma unroll
        for (int j = 0; j < 4; ++j) {
            const int p = n_w + j * 16 + l15;
#pragma unroll
            for (int r = 0; r < 4; ++r) {
                const int m = m_w + mf * 16 + rB + r;
                float v = 0.0f;
                if (ga.ci0) v += ga.ci0[(size_t)m * ga.ld0 + p];
                if (ga.ci1) v += ga.ci1[(size_t)m * ga.ld1 + p];
                accH[mf][j][r] = v;
                accL[mf][j][r] = 0.0f;
            }
        }

#pragma unroll 1
    for (int opi = 0; opi < 3; ++opi) {
        const PairOp o = ga.op[opi];
        if (o.Ahi == nullptr || o.K <= 0) continue;
        const ushort_t *aH[MF], *aL[MF], *wH[4], *wL[4];
#pragma unroll
        for (int mf = 0; mf < MF; ++mf) {
            size_t ro = (size_t)(m_w + mf * 16 + l15) * o.lda + lk8;
            aH[mf] = o.Ahi + ro; aL[mf] = o.Alo + ro;
        }
#pragma unroll
        for (int j = 0; j < 4; ++j) {
            size_t ro = (size_t)(n_w + j * 16 + l15) * o.ldw + lk8;
            wH[j] = o.Whi + ro; wL[j] = o.Wlo + ro;
        }
        const int NK = o.K >> 5;

        auto LD = [&](short8* ah, short8* al, short8* wh, short8* wl, int ks) {
#pragma unroll
            for (int mf = 0; mf < MF; ++mf) {
                ah[mf] = *(const short8*)(aH[mf] + ks * 32);
                al[mf] = *(const short8*)(aL[mf] + ks * 32);
            }
#pragma unroll
            for (int j = 0; j < 4; ++j) {
                wh[j] = *(const short8*)(wH[j] + ks * 32);
                wl[j] = *(const short8*)(wL[j] + ks * 32);
            }
        };
        auto MM = [&](short8* ah, short8* al, short8* wh, short8* wl) {
#pragma unroll
            for (int mf = 0; mf < MF; ++mf)
#pragma unroll
                for (int j = 0; j < 4; ++j) {
                    accL[mf][j] = MFH(ah[mf], wl[j], accL[mf][j]);
                    accL[mf][j] = MFH(al[mf], wh[j], accL[mf][j]);
                    accH[mf][j] = MFH(ah[mf], wh[j], accH[mf][j]);
                }
        };

        if constexpr (DEEP) {
            // 4-buffer rotation; requires NK % 4 == 0 and NK >= 8.
            short8 A0[MF], L0[MF], W0[4], V0[4];
            short8 A1[MF], L1[MF], W1[4], V1[4];
            short8 A2[MF], L2[MF], W2[4], V2[4];
            short8 A3[MF], L3[MF], W3[4], V3[4];
            LD(A0, L0, W0, V0, 0);
            LD(A1, L1, W1, V1, 1);
            LD(A2, L2, W2, V2, 2);
            LD(A3, L3, W3, V3, 3);
            int ks = 0;
            for (; ks + 8 <= NK; ks += 4) {
                MM(A0, L0, W0, V0); LD(A0, L0, W0, V0, ks + 4);
                MM(A1, L1, W1, V1); LD(A1, L1, W1, V1, ks + 5);
                MM(A2, L2, W2, V2); LD(A2, L2, W2, V2, ks + 6);
                MM(A3, L3, W3, V3); LD(A3, L3, W3, V3, ks + 7);
            }
            MM(A0, L0, W0, V0);
            MM(A1, L1, W1, V1);
            MM(A2, L2, W2, V2);
            MM(A3, L3, W3, V3);
        } else {
            short8 A0[MF], L0[MF], W0[4], V0[4];
            short8 A1[MF], L1[MF], W1[4], V1[4];
            LD(A0, L0, W0, V0, 0);
            int ks = 0;
            for (; ks + 2 < NK; ks += 2) {
                LD(A1, L1, W1, V1, ks + 1);
                MM(A0, L0, W0, V0);
                LD(A0, L0, W0, V0, ks + 2);
                MM(A1, L1, W1, V1);
            }
            LD(A1, L1, W1, V1, ks + 1);
            MM(A0, L0, W0, V0);
            MM(A1, L1, W1, V1);
        }
    }

    if (ga.mode == 1) {
        const int n = (n_w >> 6) * 16 + l15;      // neuron index
#pragma unroll
        for (int mf = 0; mf < MF; ++mf)
#pragma unroll
            for (int r = 0; r < 4; ++r) {
                const int m = m_w + mf * 16 + rB + r;
                const float gi = accH[mf][0][r] + LO_UNSCALE * accL[mf][0][r];
                const float gf = accH[mf][1][r] + LO_UNSCALE * accL[mf][1][r];
                const float gg = accH[mf][2][r] + LO_UNSCALE * accL[mf][2][r];
                const float go = accH[mf][3][r] + LO_UNSCALE * accL[mf][3][r];
                const float cold = ga.cin[(size_t)m * ga.cinLd + n];
                const float cn = sigmoidf_(gf) * cold + sigmoidf_(gi) * tanhf(gg);
                const float h  = sigmoidf_(go) * tanhf(cn);
                ga.cout[(size_t)m * ga.coutLd + n] = cn;
                hfp hp = f16_split(h);
                ga.hHi[(size_t)m * ga.hLd + n] = hp.hi;
                ga.hLo[(size_t)m * ga.hLd + n] = hp.lo;
            }
    } else {
#pragma unroll
        for (int mf = 0; mf < MF; ++mf)
#pragma unroll
            for (int j = 0; j < 4; ++j) {
                const int p = n_w + j * 16 + l15;
#pragma unroll
                for (int r = 0; r < 4; ++r) {
                    const int m = m_w + mf * 16 + rB + r;
                    const float v = accH[mf][j][r] + LO_UNSCALE * accL[mf][j][r];
                    int dst = m;
                    if (ga.mode == 2) dst = ((m & (B - 1)) << 6) + (m >> 8);  // b*T + t
                    if (ga.out) ga.out[(size_t)dst * ga.outLd + p] = v;
                    if (ga.pHi) {
                        hfp vp = f16_split(v);
                        ga.pHi[(size_t)m * ga.pLd + p] = vp.hi;
                        ga.pLo[(size_t)m * ga.pLd + p] = vp.lo;
                    }
                }
            }
    }
}

// layernorm(mu), softplus(std), z = mu+eps*std -> c0,c1 (fp32) and z f16 pairs
__global__ void latent2(float* __restrict__ mu, float* __restrict__ sd,
                        const float* __restrict__ eps, float* __restrict__ c0,
                        float* __restrict__ c1, ushort_t* __restrict__ zh,
                        ushort_t* __restrict__ zl)
{
    const int b = blockIdx.x, l = threadIdx.x;
    float* mrow = mu + (size_t)b * L;
    float4 v0 = *(const float4*)(mrow + l * 4);
    float4 v1 = *(const float4*)(mrow + 256 + l * 4);
    float s = v0.x + v0.y + v0.z + v0.w + v1.x + v1.y + v1.z + v1.w;
    float q = v0.x * v0.x + v0.y * v0.y + v0.z * v0.z + v0.w * v0.w
            + v1.x * v1.x + v1.y * v1.y + v1.z * v1.z + v1.w * v1.w;
#pragma unroll
    for (int off = 32; off; off >>= 1) { s += __shfl_xor(s, off); q += __shfl_xor(q, off); }
    const float mean = s * (1.0f / 512.0f);
    const float var  = q * (1.0f / 512.0f) - mean * mean;
    const float inv  = rsqrtf(var + 1e-5f);
    v0.x = (v0.x - mean) * inv; v0.y = (v0.y - mean) * inv; v0.z = (v0.z - mean) * inv; v0.w = (v0.w - mean) * inv;
    v1.x = (v1.x - mean) * inv; v1.y = (v1.y - mean) * inv; v1.z = (v1.z - mean) * inv; v1.w = (v1.w - mean) * inv;
    *(float4*)(mrow + l * 4) = v0;
    *(float4*)(mrow + 256 + l * 4) = v1;

    float* srow = sd + (size_t)b * L;
    float4 s0 = *(const float4*)(srow + l * 4);
    float4 s1 = *(const float4*)(srow + 256 + l * 4);
    s0.x = fmaxf(s0.x, 0.0f) + log1pf(expf(-fabsf(s0.x)));
    s0.y = fmaxf(s0.y, 0.0f) + log1pf(expf(-fabsf(s0.y)));
    s0.z = fmaxf(s0.z, 0.0f) + log1pf(expf(-fabsf(s0.z)));
    s0.w = fmaxf(s0.w, 0.0f) + log1pf(expf(-fabsf(s0.w)));
    s1.x = fmaxf(s1.x, 0.0f) + log1pf(expf(-fabsf(s1.x)));
    s1.y = fmaxf(s1.y, 0.0f) + log1pf(expf(-fabsf(s1.y)));
    s1.z = fmaxf(s1.z, 0.0f) + log1pf(expf(-fabsf(s1.z)));
    s1.w = fmaxf(s1.w, 0.0f) + log1pf(expf(-fabsf(s1.w)));
    *(float4*)(srow + l * 4) = s0;
    *(float4*)(srow + 256 + l * 4) = s1;

    const float* erow = eps + (size_t)b * L;
    float4 e0 = *(const float4*)(erow + l * 4);
    float4 e1 = *(const float4*)(erow + 256 + l * 4);
    float4 z0, z1;
    z0.x = v0.x + e0.x * s0.x; z0.y = v0.y + e0.y * s0.y; z0.z = v0.z + e0.z * s0.z; z0.w = v0.w + e0.w * s0.w;
    z1.x = v1.x + e1.x * s1.x; z1.y = v1.y + e1.y * s1.y; z1.z = v1.z + e1.z * s1.z; z1.w = v1.w + e1.w * s1.w;
    *(float4*)(c0 + (size_t)b * L + l * 4) = z0;
    *(float4*)(c0 + (size_t)b * L + 256 + l * 4) = z1;
    *(float4*)(c1 + (size_t)b * L + l * 4) = z0;
    *(float4*)(c1 + (size_t)b * L + 256 + l * 4) = z1;
    ushort4_t h, lo;
    hfp a;
    a = f16_split(z0.x); h[0] = a.hi; lo[0] = a.lo;
    a = f16_split(z0.y); h[1] = a.hi; lo[1] = a.lo;
    a = f16_split(z0.z); h[2] = a.hi; lo[2] = a.lo;
    a = f16_split(z0.w); h[3] = a.hi; lo[3] = a.lo;
    *(ushort4_t*)(zh + (size_t)b * L + l * 4) = h;
    *(ushort4_t*)(zl + (size_t)b * L + l * 4) = lo;
    a = f16_split(z1.x); h[0] = a.hi; lo[0] = a.lo;
    a = f16_split(z1.y); h[1] = a.hi; lo[1] = a.lo;
    a = f16_split(z1.z); h[2] = a.hi; lo[2] = a.lo;
    a = f16_split(z1.w); h[3] = a.hi; lo[3] = a.lo;
    *(ushort4_t*)(zh + (size_t)b * L + 256 + l * 4) = h;
    *(ushort4_t*)(zl + (size_t)b * L + 256 + l * 4) = lo;
}

// in-place softmax + argmax over all B*T rows; one wave per row.
__global__ void softmax_all(float* __restrict__ prob, float* __restrict__ label)
{
    const int r = blockIdx.x, l = threadIdx.x;
    float* row = prob + (size_t)r * D;
    float4 x0 = *(const float4*)(row + l * 4);
    float4 x1 = *(const float4*)(row + 256 + l * 4);
    float m = x0.x; int mi = l * 4;
    { float v; int i;
      v = x0.y; i = l * 4 + 1;       if (v > m) { m = v; mi = i; }
      v = x0.z; i = l * 4 + 2;       if (v > m) { m = v; mi = i; }
      v = x0.w; i = l * 4 + 3;       if (v > m) { m = v; mi = i; }
      v = x1.x; i = 256 + l * 4;     if (v > m) { m = v; mi = i; }
      v = x1.y; i = 256 + l * 4 + 1; if (v > m) { m = v; mi = i; }
      v = x1.z; i = 256 + l * 4 + 2; if (v > m) { m = v; mi = i; }
      v = x1.w; i = 256 + l * 4 + 3; if (v > m) { m = v; mi = i; } }
#pragma unroll
    for (int off = 32; off; off >>= 1) {
        float om = __shfl_xor(m, off);
        int   oi = __shfl_xor(mi, off);
        if (om > m || (om == m && oi < mi)) { m = om; mi = oi; }
    }
    float4 e0, e1;
    e0.x = expf(x0.x - m); e0.y = expf(x0.y - m); e0.z = expf(x0.z - m); e0.w = expf(x0.w - m);
    e1.x = expf(x1.x - m); e1.y = expf(x1.y - m); e1.z = expf(x1.z - m); e1.w = expf(x1.w - m);
    float s = e0.x + e0.y + e0.z + e0.w + e1.x + e1.y + e1.z + e1.w;
#pragma unroll
    for (int off = 32; off; off >>= 1) s += __shfl_xor(s, off);
    const float inv = 1.0f / s;
    e0.x *= inv; e0.y *= inv; e0.z *= inv; e0.w *= inv;
    e1.x *= inv; e1.y *= inv; e1.z *= inv; e1.w *= inv;
    *(float4*)(row + l * 4) = e0;
    *(float4*)(row + 256 + l * 4) = e1;
    if (l == 0) label[r] = (float)mi;
}

// ---------------------------------------------------------------------------
extern "C" void kernel_launch(void* const* d_in, const int* in_sizes, int n_in,
                              void* d_out, int out_size, void* d_ws, size_t ws_size,
                              hipStream_t stream)
{
    const float* x       = (const float*)d_in[0];
    const float* eps     = (const float*)d_in[1];
    const float* We_ih_f = (const float*)d_in[2];
    const float* We_hh_f = (const float*)d_in[3];
    const float* be_ih_f = (const float*)d_in[4];
    const float* be_hh_f = (const float*)d_in[5];
    const float* We_ih_b = (const float*)d_in[6];
    const float* We_hh_b = (const float*)d_in[7];
    const float* be_ih_b = (const float*)d_in[8];
    const float* be_hh_b = (const float*)d_in[9];
    const float* Wmu     = (const float*)d_in[10];
    const float* bmu     = (const float*)d_in[11];
    const float* Wstd    = (const float*)d_in[12];
    const float* bstd    = (const float*)d_in[13];
    const float* Wc_ih0  = (const float*)d_in[14];
    const float* Wc_hh0  = (const float*)d_in[15];
    const float* bc_ih0  = (const float*)d_in[16];
    const float* bc_hh0  = (const float*)d_in[17];
    const float* Wc_ih1  = (const float*)d_in[18];
    const float* Wc_hh1  = (const float*)d_in[19];
    const float* bc_ih1  = (const float*)d_in[20];
    const float* bc_hh1  = (const float*)d_in[21];
    const float* Wcl     = (const float*)d_in[22];
    const float* bcl     = (const float*)d_in[23];
    const float* Wd_ih0  = (const float*)d_in[24];
    const float* Wd_hh0  = (const float*)d_in[25];
    const float* bd_ih0  = (const float*)d_in[26];
    const float* bd_hh0  = (const float*)d_in[27];
    const float* Wd_ih1  = (const float*)d_in[28];
    const float* Wd_hh1  = (const float*)d_in[29];
    const float* bd_ih1  = (const float*)d_in[30];
    const float* bd_hh1  = (const float*)d_in[31];
    const float* Wlog    = (const float*)d_in[32];
    const float* blog    = (const float*)d_in[33];
    (void)in_sizes; (void)n_in; (void)out_size;

    float* out      = (float*)d_out;
    float* prob_out = out;
    float* mu_out   = out + (size_t)B * T * D;
    float* std_out  = mu_out + (size_t)B * L;
    float* lab_out  = std_out + (size_t)B * L;

    // ---------------- workspace layout ----------------
    char* cur = (char*)d_ws;
    auto alignup = [&]() { cur = (char*)(((uintptr_t)cur + 255) & ~(uintptr_t)255); };
    auto aU = [&](size_t elems) { alignup(); ushort_t* p = (ushort_t*)cur; cur += elems * 2; return p; };
    auto aF = [&](size_t elems) { alignup(); float* p = (float*)cur; cur += elems * 4; return p; };

    // weights (hi, lo planes)
    ushort_t* WefIh = aU((size_t)4*HE*D);  ushort_t* WefIl = aU((size_t)4*HE*D);
    ushort_t* WefHh = aU((size_t)4*HE*HE); ushort_t* WefHl = aU((size_t)4*HE*HE);
    ushort_t* WebIh = aU((size_t)4*HE*D);  ushort_t* WebIl = aU((size_t)4*HE*D);
    ushort_t* WebHh = aU((size_t)4*HE*HE); ushort_t* WebHl = aU((size_t)4*HE*HE);
    ushort_t* Wc0Ih = aU((size_t)4*L*L);   ushort_t* Wc0Il = aU((size_t)4*L*L);
    ushort_t* Wc0Hh = aU((size_t)4*L*L);   ushort_t* Wc0Hl = aU((size_t)4*L*L);
    ushort_t* Wc1Ih = aU((size_t)4*L*L);   ushort_t* Wc1Il = aU((size_t)4*L*L);
    ushort_t* Wc1Hh = aU((size_t)4*L*L);   ushort_t* Wc1Hl = aU((size_t)4*L*L);
    ushort_t* Wd0Ih = aU((size_t)4*L*(D+L)); ushort_t* Wd0Il = aU((size_t)4*L*(D+L));
    ushort_t* Wd0Hh = aU((size_t)4*L*L);   ushort_t* Wd0Hl = aU((size_t)4*L*L);
    ushort_t* Wd1Ih = aU((size_t)4*L*L);   ushort_t* Wd1Il = aU((size_t)4*L*L);
    ushort_t* Wd1Hh = aU((size_t)4*L*L);   ushort_t* Wd1Hl = aU((size_t)4*L*L);
    ushort_t* WmuH  = aU((size_t)L*2*HE);  ushort_t* WmuL  = aU((size_t)L*2*HE);
    ushort_t* WstdH = aU((size_t)L*2*HE);  ushort_t* WstdL = aU((size_t)L*2*HE);
    ushort_t* WclH  = aU((size_t)L*L);     ushort_t* WclL  = aU((size_t)L*L);
    ushort_t* WlogH = aU((size_t)D*L);     ushort_t* WlogL = aU((size_t)D*L);
    // activations
    ushort_t* xh = aU((size_t)T*B*D);      ushort_t* xl = aU((size_t)T*B*D);
    ushort_t* hfh[2] = { aU((size_t)B*HE), aU((size_t)B*HE) };
    ushort_t* hfl[2] = { aU((size_t)B*HE), aU((size_t)B*HE) };
    ushort_t* hbh[2] = { aU((size_t)B*HE), aU((size_t)B*HE) };
    ushort_t* hbl[2] = { aU((size_t)B*HE), aU((size_t)B*HE) };
    ushort_t* zh = aU((size_t)B*L);        ushort_t* zl = aU((size_t)B*L);
    ushort_t* h0h[2] = { aU((size_t)B*L), aU((size_t)B*L) };
    ushort_t* h0l[2] = { aU((size_t)B*L), aU((size_t)B*L) };
    ushort_t* ftsH = aU((size_t)B*4*L);    ushort_t* ftsL = aU((size_t)B*4*L);
    ushort_t* featH = aU((size_t)B*4*L);   ushort_t* featL = aU((size_t)B*4*L);
    ushort_t* hd1h[2] = { aU((size_t)B*L), aU((size_t)B*L) };
    ushort_t* hd1l[2] = { aU((size_t)B*L), aU((size_t)B*L) };
    ushort_t* slabH = aU((size_t)T*B*L);   ushort_t* slabL = aU((size_t)T*B*L);
    // fp32 state
    float* cf   = aF((size_t)B*HE);
    float* cb   = aF((size_t)B*HE);
    float* zbuf = aF((size_t)B*HE);
    float* c0   = aF((size_t)B*L);
    float* c1   = aF((size_t)B*L);
    float* cd1  = aF((size_t)B*L);
    float* cd2  = aF((size_t)B*L);
    float* featF = aF((size_t)B*4*L);
    float* bEF = aF((size_t)4*HE);
    float* bEB = aF((size_t)4*HE);
    float* bC0 = aF((size_t)4*L);
    float* bC1 = aF((size_t)4*L);
    float* bD0 = aF((size_t)4*L);
    float* bD1 = aF((size_t)4*L);
    const size_t need = (size_t)(cur - (char*)d_ws);
    if (need > ws_size) return;   // ws is sized by the harness; R3-R6 all fit

    // ==================== fp16x3 MFMA path ====================
    auto PK = [&](const float* s, ushort_t* h, ushort_t* l, int Np, int K, int H) {
        int tot = Np * (K >> 2);
        pack_w<<<(tot + 255) / 256, 256, 0, stream>>>(s, h, l, Np, K, H);
    };
    PK(We_ih_f, WefIh, WefIl, 4*HE, D, HE);
    PK(We_hh_f, WefHh, WefHl, 4*HE, HE, HE);
    PK(We_ih_b, WebIh, WebIl, 4*HE, D, HE);
    PK(We_hh_b, WebHh, WebHl, 4*HE, HE, HE);
    PK(Wc_ih0, Wc0Ih, Wc0Il, 4*L, L, L);
    PK(Wc_hh0, Wc0Hh, Wc0Hl, 4*L, L, L);
    PK(Wc_ih1, Wc1Ih, Wc1Il, 4*L, L, L);
    PK(Wc_hh1, Wc1Hh, Wc1Hl, 4*L, L, L);
    PK(Wd_ih0, Wd0Ih, Wd0Il, 4*L, D+L, L);
    PK(Wd_hh0, Wd0Hh, Wd0Hl, 4*L, L, L);
    PK(Wd_ih1, Wd1Ih, Wd1Il, 4*L, L, L);
    PK(Wd_hh1, Wd1Hh, Wd1Hl, 4*L, L, L);
    PK(Wmu,  WmuH,  WmuL,  L, 2*HE, 0);
    PK(Wstd, WstdH, WstdL, L, 2*HE, 0);
    PK(Wcl,  WclH,  WclL,  L, L, 0);
    PK(Wlog, WlogH, WlogL, D, L, 0);
    pack_bias<<<(4*HE + 255) / 256, 256, 0, stream>>>(be_ih_f, be_hh_f, bEF, HE);
    pack_bias<<<(4*HE + 255) / 256, 256, 0, stream>>>(be_ih_b, be_hh_b, bEB, HE);
    pack_bias<<<(4*L + 255) / 256, 256, 0, stream>>>(bc_ih0, bc_hh0, bC0, L);
    pack_bias<<<(4*L + 255) / 256, 256, 0, stream>>>(bc_ih1, bc_hh1, bC1, L);
    pack_bias<<<(4*L + 255) / 256, 256, 0, stream>>>(bd_ih0, bd_hh0, bD0, L);
    pack_bias<<<(4*L + 255) / 256, 256, 0, stream>>>(bd_ih1, bd_hh1, bD1, L);
    conv_x<<<(T*B*D/4 + 255) / 256, 256, 0, stream>>>(x, xh, xl);
    (void)hipMemsetAsync(zbuf, 0, (size_t)B * HE * sizeof(float), stream);

    // ---------- encoder: R5 tile (64x128, 4 waves) + DEEP=4 pipeline ----------
    for (int t = 0; t < T; ++t) {
        MArgs f{};
        f.op[0] = { xh + (size_t)t*B*D, xl + (size_t)t*B*D, D, WefIh, WefIl, D, D };
        if (t) f.op[1] = { hfh[t&1], hfl[t&1], HE, WefHh, WefHl, HE, HE };
        f.ci0 = bEF; f.ld0 = 0;
        f.mode = 1;
        f.cin = t ? cf : zbuf; f.cinLd = HE;
        f.cout = cf; f.coutLd = HE;
        f.hHi = hfh[(t+1)&1]; f.hLo = hfl[(t+1)&1]; f.hLd = HE;
        MArgs b = f;
        b.op[0] = { xh + (size_t)(T-1-t)*B*D, xl + (size_t)(T-1-t)*B*D, D, WebIh, WebIl, D, D };
        if (t) b.op[1] = { hbh[t&1], hbl[t&1], HE, WebHh, WebHl, HE, HE };
        b.ci0 = bEB;
        b.cin = t ? cb : zbuf;
        b.cout = cb;
        b.hHi = hbh[(t+1)&1]; b.hLo = hbl[(t+1)&1];
        gemm_hx<2,2,2,1><<<dim3(4*HE/128, B/64, 2), 256, 0, stream>>>(f, b);
    }

    // ---------- latent (R5 config) ----------
    {
        MArgs m{};
        m.op[0] = { hfh[0], hfl[0], HE, WmuH, WmuL, 2*HE, HE };
        m.op[1] = { hbh[0], hbl[0], HE, WmuH + HE, WmuL + HE, 2*HE, HE };
        m.ci0 = bmu; m.ld0 = 0; m.mode = 0; m.out = mu_out; m.outLd = L;
        MArgs s = m;
        s.op[0].Whi = WstdH; s.op[0].Wlo = WstdL;
        s.op[1].Whi = WstdH + HE; s.op[1].Wlo = WstdL + HE;
        s.ci0 = bstd; s.out = std_out;
        gemm_hx<1,1,1,0><<<dim3(L/64, B/16, 2), 64, 0, stream>>>(m, s);
        latent2<<<B, 64, 0, stream>>>(mu_out, std_out, eps, c0, c1, zh, zl);
    }

    // ---------- conductor (R5 config) ----------
    for (int bar = 0; bar < 4; ++bar) {
        MArgs a{};
        a.op[0] = { zh, zl, L, Wc0Ih, Wc0Il, L, L };
        a.op[1] = { bar ? h0h[(bar-1)&1] : zh, bar ? h0l[(bar-1)&1] : zl, L, Wc0Hh, Wc0Hl, L, L };
        a.ci0 = bC0; a.ld0 = 0; a.mode = 1;
        a.cin = c0; a.cinLd = L; a.cout = c0; a.coutLd = L;
        a.hHi = h0h[bar&1]; a.hLo = h0l[bar&1]; a.hLd = L;
        gemm_hx<1,1,1,0><<<dim3(4*L/64, B/16, 1), 64, 0, stream>>>(a, a);
        MArgs a2{};
        a2.op[0] = { h0h[bar&1], h0l[bar&1], L, Wc1Ih, Wc1Il, L, L };
        if (bar) a2.op[1] = { ftsH + (size_t)(bar-1)*L, ftsL + (size_t)(bar-1)*L, 4*L, Wc1Hh, Wc1Hl, L, L };
        else     a2.op[1] = { zh, zl, L, Wc1Hh, Wc1Hl, L, L };
        a2.ci0 = bC1; a2.ld0 = 0; a2.mode = 1;
        a2.cin = c1; a2.cinLd = L; a2.cout = c1; a2.coutLd = L;
        a2.hHi = ftsH + (size_t)bar*L; a2.hLo = ftsL + (size_t)bar*L; a2.hLd = 4*L;
        gemm_hx<1,1,1,0><<<dim3(4*L/64, B/16, 1), 64, 0, stream>>>(a2, a2);
    }
    {   // feat = feats @ Wcl^T + bcl (fp32 + pairs)
        MArgs af{};
        af.op[0] = { ftsH, ftsL, L, WclH, WclL, L, L };
        af.ci0 = bcl; af.ld0 = 0; af.mode = 0;
        af.out = featF; af.outLd = L;
        af.pHi = featH; af.pLo = featL; af.pLd = L;
        gemm_hx<1,1,1,0><<<dim3(L/64, B*4/16, 1), 64, 0, stream>>>(af, af);
    }

    // ---------- decoder (R5 config) ----------
    for (int t = 0; t < T; ++t) {
        const int bar = t >> 4;
        const bool rs = (t & 15) == 0;
        const float* cinF = featF + (size_t)bar * L;

        MArgs g1{};
        if (t) g1.op[0] = { xh + (size_t)(t-1)*B*D, xl + (size_t)(t-1)*B*D, D, Wd0Ih, Wd0Il, D+L, D };
        g1.op[1] = { featH + (size_t)bar*L, featL + (size_t)bar*L, 4*L, Wd0Ih + D, Wd0Il + D, D+L, L };
        if (rs) g1.op[2] = { featH + (size_t)bar*L, featL + (size_t)bar*L, 4*L, Wd0Hh, Wd0Hl, L, L };
        else    g1.op[2] = { hd1h[(t-1)&1], hd1l[(t-1)&1], L, Wd0Hh, Wd0Hl, L, L };
        g1.ci0 = bD0; g1.ld0 = 0; g1.mode = 1;
        g1.cin = rs ? cinF : cd1; g1.cinLd = rs ? 4*L : L;
        g1.cout = cd1; g1.coutLd = L;
        g1.hHi = hd1h[t&1]; g1.hLo = hd1l[t&1]; g1.hLd = L;
        gemm_hx<1,1,1,0><<<dim3(4*L/64, B/16, 1), 64, 0, stream>>>(g1, g1);

        MArgs g2{};
        g2.op[0] = { hd1h[t&1], hd1l[t&1], L, Wd1Ih, Wd1Il, L, L };
        if (rs) g2.op[1] = { featH + (size_t)bar*L, featL + (size_t)bar*L, 4*L, Wd1Hh, Wd1Hl, L, L };
        else    g2.op[1] = { slabH + (size_t)(t-1)*B*L, slabL + (size_t)(t-1)*B*L, L, Wd1Hh, Wd1Hl, L, L };
        g2.ci0 = bD1; g2.ld0 = 0; g2.mode = 1;
        g2.cin = rs ? cinF : cd2; g2.cinLd = rs ? 4*L : L;
        g2.cout = cd2; g2.coutLd = L;
        g2.hHi = slabH + (size_t)t*B*L; g2.hLo = slabL + (size_t)t*B*L; g2.hLd = L;
        gemm_hx<1,1,1,0><<<dim3(4*L/64, B/16, 1), 64, 0, stream>>>(g2, g2);
    }

    // ---------- logits (batched) + softmax ----------
    {
        MArgs lg{};
        lg.op[0] = { slabH, slabL, L, WlogH, WlogL, L, L };
        lg.ci0 = blog; lg.ld0 = 0; lg.mode = 2;
        lg.out = prob_out; lg.outLd = D;
        gemm_hx<2,2,2,0><<<dim3(D/128, T*B/64, 1), 256, 0, stream>>>(lg, lg);
    }
    softmax_all<<<B * T, 64, 0, stream>>>(prob_out, lab_out);
}